// Round 2
// baseline (259.915 us; speedup 1.0000x reference)
//
#include <hip/hip_runtime.h>
#include <math.h>

// Problem dims (fixed by setup_inputs)
#define B_N 256
#define C_N 1152
#define I_N 8
#define N_N 10
#define D_N 16

constexpr int C_CHUNKS = 48;             // parallelism over the c-reduction
constexpr int C_PER    = C_N / C_CHUNKS; // 24
constexpr int KC       = 4;              // c's staged per LDS round
constexpr int ROUNDS   = C_PER / KC;     // 6
constexpr int B_TILE   = 16;             // batch elements per block
constexpr int BLOCK    = 256;
constexpr int WS_STRIDE = 132;           // 128+4: slots 0..7 hit banks 0,4,..28 (distinct)
constexpr int WS_PER_C  = N_N * WS_STRIDE;  // 1320
constexpr int XS_STRIDE = C_PER * I_N + 4;  // 196
constexpr int CB_STRIDE = 164;           // comb row stride (160+4, conflict-free write/read)

// ws layout: vsum [B,N,D] floats, then p_s [C_CHUNKS][B][N][D] floats (~8.03 MB)

// Lane map (conflict-free): b_lane = lane&3, slot = lane>>2. A 32-lane LDS phase
// holds slots 0..7 only -> Ws banks 4n mod 32 all distinct (was 2-way n=0/8,1/9).
// RB=2: each lane computes b_lane and b_lane+4 from ONE Ws read (halves LDS issue).
// Warps split the c range by parity; partial s combined through LDS `comb` at end.
template <bool FIRST>
__global__ __launch_bounds__(BLOCK)
void route_pass(const float* __restrict__ x, const float* __restrict__ W,
                const float* __restrict__ vsum, float* __restrict__ p_s)
{
    __shared__ float xs[B_TILE * XS_STRIDE];
    __shared__ float Ws[KC * WS_PER_C];
    __shared__ float comb[B_TILE * CB_STRIDE];

    const int tid    = threadIdx.x;
    const int warp   = tid >> 6;
    const int lane   = tid & 63;
    const int b_lane = lane & 3;
    const int slot   = lane >> 2;
    const int parity = warp & 1;     // which cc's this warp computes
    const int b_oct  = warp >> 1;    // which 8 b's this warp covers
    const bool active = (slot < N_N);
    const int  n     = active ? slot : (N_N - 1);  // idle lanes shadow n=9 (broadcast)
    const int  chunk = blockIdx.x;
    const int  gb0   = blockIdx.y * B_TILE;
    const int  bl1   = b_oct * 8 + b_lane;
    const int  bl2   = bl1 + 4;
    const int  gb1   = gb0 + bl1;
    const int  gb2   = gb0 + bl2;
    const int  cbase = chunk * C_PER;

    // ---- stage x tile once (coalesced float4) ----
    {
        const float4* x4 = reinterpret_cast<const float4*>(x);
        for (int f = tid; f < (B_TILE * C_PER * I_N) / 4; f += BLOCK) {
            const int e   = f * 4;
            const int bl  = e / (C_PER * I_N);
            const int off = e - bl * (C_PER * I_N);
            float4 v = x4[(size_t)(gb0 + bl) * (C_N * I_N / 4) + (size_t)cbase * 2 + (off >> 2)];
            *reinterpret_cast<float4*>(&xs[bl * XS_STRIDE + off]) = v;
        }
    }

    // ---- vsum fragments in registers (2 b's) ----
    float vs1[D_N], vs2[D_N];
    if (!FIRST) {
        const float* vp1 = vsum + ((size_t)gb1 * N_N + n) * D_N;
        const float* vp2 = vsum + ((size_t)gb2 * N_N + n) * D_N;
        #pragma unroll
        for (int d = 0; d < D_N; d += 4) {
            float4 a = *reinterpret_cast<const float4*>(vp1 + d);
            vs1[d] = a.x; vs1[d+1] = a.y; vs1[d+2] = a.z; vs1[d+3] = a.w;
            float4 b = *reinterpret_cast<const float4*>(vp2 + d);
            vs2[d] = b.x; vs2[d+1] = b.y; vs2[d+2] = b.z; vs2[d+3] = b.w;
        }
    }

    float s1[D_N], s2[D_N];
    #pragma unroll
    for (int d = 0; d < D_N; ++d) { s1[d] = 0.f; s2[d] = 0.f; }

    const float4* W4 = reinterpret_cast<const float4*>(W);

    for (int round = 0; round < ROUNDS; ++round) {
        __syncthreads();
        // ---- stage W for KC c's: 5120 floats, coalesced float4 ----
        const int c0 = cbase + round * KC;
        for (int f = tid; f < (KC * N_N * 128) / 4; f += BLOCK) {
            const int e  = f * 4;
            const int cc = e / (N_N * 128);
            const int r  = e - cc * (N_N * 128);
            const int nn = r >> 7;
            const int k  = r & 127;
            float4 v = W4[(size_t)nn * (C_N * 128 / 4) + (size_t)(c0 + cc) * 32 + (k >> 2)];
            *reinterpret_cast<float4*>(&Ws[cc * WS_PER_C + nn * WS_STRIDE + k]) = v;
        }
        __syncthreads();

        // this warp computes cc = parity, parity+2 within the round
        #pragma unroll
        for (int half = 0; half < KC / 2; ++half) {
            const int ccl  = half * 2 + parity;
            const int crel = round * KC + ccl;
            const float* xp1 = &xs[bl1 * XS_STRIDE + crel * I_N];
            const float* xp2 = &xs[bl2 * XS_STRIDE + crel * I_N];
            const float4 xa1 = *reinterpret_cast<const float4*>(xp1);
            const float4 xb1 = *reinterpret_cast<const float4*>(xp1 + 4);
            const float4 xa2 = *reinterpret_cast<const float4*>(xp2);
            const float4 xb2 = *reinterpret_cast<const float4*>(xp2 + 4);
            const float* wp = &Ws[ccl * WS_PER_C + n * WS_STRIDE];

            float u1[D_N], u2[D_N];
            #pragma unroll
            for (int d = 0; d < D_N; ++d) {
                const float4 wa = *reinterpret_cast<const float4*>(wp + d * 8);
                const float4 wb = *reinterpret_cast<const float4*>(wp + d * 8 + 4);
                u1[d] = wa.x * xa1.x + wa.y * xa1.y + wa.z * xa1.z + wa.w * xa1.w
                      + wb.x * xb1.x + wb.y * xb1.y + wb.z * xb1.z + wb.w * xb1.w;
                u2[d] = wa.x * xa2.x + wa.y * xa2.y + wa.z * xa2.z + wa.w * xa2.w
                      + wb.x * xb2.x + wb.y * xb2.y + wb.z * xb2.z + wb.w * xb2.w;
            }

            if (FIRST) {
                #pragma unroll
                for (int d = 0; d < D_N; ++d) {
                    s1[d] += 0.1f * u1[d];
                    s2[d] += 0.1f * u2[d];
                }
            } else {
                float l1 = 0.f, l2 = 0.f;
                #pragma unroll
                for (int d = 0; d < D_N; ++d) { l1 += u1[d] * vs1[d]; l2 += u2[d] * vs2[d]; }
                if (!active) { l1 = -1e30f; l2 = -1e30f; }
                float m1 = l1, m2 = l2;
                #pragma unroll
                for (int off = 4; off < 64; off <<= 1) {
                    m1 = fmaxf(m1, __shfl_xor(m1, off));
                    m2 = fmaxf(m2, __shfl_xor(m2, off));
                }
                const float e1 = active ? __expf(l1 - m1) : 0.f;
                const float e2 = active ? __expf(l2 - m2) : 0.f;
                float Z1 = e1, Z2 = e2;
                #pragma unroll
                for (int off = 4; off < 64; off <<= 1) {
                    Z1 += __shfl_xor(Z1, off);
                    Z2 += __shfl_xor(Z2, off);
                }
                const float c1 = e1 / Z1;
                const float c2 = e2 / Z2;
                #pragma unroll
                for (int d = 0; d < D_N; ++d) {
                    s1[d] += c1 * u1[d];
                    s2[d] += c2 * u2[d];
                }
            }
        }
    }

    // ---- combine parity-1 partials into parity-0 via LDS, store p_s ----
    __syncthreads();
    if (parity == 1 && active) {
        float* cp1 = &comb[bl1 * CB_STRIDE + n * D_N];
        float* cp2 = &comb[bl2 * CB_STRIDE + n * D_N];
        #pragma unroll
        for (int d = 0; d < D_N; d += 4) {
            *reinterpret_cast<float4*>(cp1 + d) = make_float4(s1[d], s1[d+1], s1[d+2], s1[d+3]);
            *reinterpret_cast<float4*>(cp2 + d) = make_float4(s2[d], s2[d+1], s2[d+2], s2[d+3]);
        }
    }
    __syncthreads();
    if (parity == 0 && active) {
        const float* cp1 = &comb[bl1 * CB_STRIDE + n * D_N];
        const float* cp2 = &comb[bl2 * CB_STRIDE + n * D_N];
        float* op1 = &p_s[(((size_t)chunk * B_N + gb1) * N_N + n) * D_N];
        float* op2 = &p_s[(((size_t)chunk * B_N + gb2) * N_N + n) * D_N];
        #pragma unroll
        for (int d = 0; d < D_N; d += 4) {
            float4 a = *reinterpret_cast<const float4*>(cp1 + d);
            float4 b = *reinterpret_cast<const float4*>(cp2 + d);
            *reinterpret_cast<float4*>(op1 + d) =
                make_float4(s1[d] + a.x, s1[d+1] + a.y, s1[d+2] + a.z, s1[d+3] + a.w);
            *reinterpret_cast<float4*>(op2 + d) =
                make_float4(s2[d] + b.x, s2[d+1] + b.y, s2[d+2] + b.z, s2[d+3] + b.w);
        }
    }
}

// Sum partials over chunks, squash, then: phase0 vsum=v; phase1 vsum+=v; phase2 out=v.
__global__ __launch_bounds__(BLOCK)
void reduce_squash(const float* __restrict__ p_s, float* __restrict__ vsum,
                   float* __restrict__ out, int phase)
{
    const int tid = threadIdx.x;
    const int lg  = tid >> 4;
    const int d   = tid & 15;
    const int gg  = blockIdx.x * 16 + lg;   // 0..2559 == b*10+n

    float s = 0.f;
    for (int cc = 0; cc < C_CHUNKS; ++cc)
        s += p_s[((size_t)cc * (B_N * N_N) + gg) * D_N + d];

    float sq = s * s;
    #pragma unroll
    for (int off = 1; off < 16; off <<= 1) sq += __shfl_xor(sq, off, 64);

    const float scale = (sq / (1.f + sq)) / (sqrtf(sq) + 1e-8f);
    const float v = scale * s;

    if (phase == 0)      vsum[(size_t)gg * D_N + d] = v;
    else if (phase == 1) vsum[(size_t)gg * D_N + d] += v;
    else                 out[(size_t)gg * D_N + d] = v;
}

extern "C" void kernel_launch(void* const* d_in, const int* in_sizes, int n_in,
                              void* d_out, int out_size, void* d_ws, size_t ws_size,
                              hipStream_t stream)
{
    const float* x = (const float*)d_in[0];
    const float* W = (const float*)d_in[1];
    float* out  = (float*)d_out;
    float* vsum = (float*)d_ws;                         // B*N*D floats
    float* p_s  = vsum + (size_t)B_N * N_N * D_N;       // C_CHUNKS*B*N*D floats

    dim3 grid(C_CHUNKS, B_N / B_TILE);
    dim3 blk(BLOCK);
    dim3 rgrid((B_N * N_N) / 16);

    // pass 0: coef = 1/N (softmax of zero logits) -> v0
    route_pass<true><<<grid, blk, 0, stream>>>(x, W, nullptr, p_s);
    reduce_squash<<<rgrid, blk, 0, stream>>>(p_s, vsum, out, 0);
    // pass 1: logits = dot(u_hat, v0) -> v1, vsum = v0+v1
    route_pass<false><<<grid, blk, 0, stream>>>(x, W, vsum, p_s);
    reduce_squash<<<rgrid, blk, 0, stream>>>(p_s, vsum, out, 1);
    // pass 2: logits = dot(u_hat, v0+v1) -> output v2
    route_pass<false><<<grid, blk, 0, stream>>>(x, W, vsum, p_s);
    reduce_squash<<<rgrid, blk, 0, stream>>>(p_s, vsum, out, 2);
}

// Round 3
// 176.055 us; speedup vs baseline: 1.4763x; 1.4763x over previous
//
#include <hip/hip_runtime.h>
#include <math.h>

// Problem dims (fixed by setup_inputs)
#define B_N 256
#define C_N 1152
#define I_N 8
#define N_N 10
#define D_N 16

constexpr int C_CHUNKS = 48;             // parallelism over the c-reduction
constexpr int C_PER    = C_N / C_CHUNKS; // 24
constexpr int KC       = 3;              // c's staged per LDS round
constexpr int ROUNDS   = C_PER / KC;     // 8
constexpr int B_TILE   = 16;             // batch elements per block
constexpr int BLOCK    = 256;
constexpr int WS_STRIDE = 132;           // 128+4: slots 0..7 -> banks 4n (distinct)
constexpr int WS_PER_C  = N_N * WS_STRIDE;  // 1320
constexpr int XS_STRIDE = C_PER * I_N + 4;  // 196

// ws layout: vsum [B,N,D] floats, then p_s [C_CHUNKS][B][N][D] floats (~8.03 MB)

// Lane map (proven conflict-free in R2): b_lane = lane&3, slot = lane>>2.
// RB=1 (one b per lane) keeps VGPR ~100 for 4-5 waves/SIMD (R2's 212 was the regression).
// W is stored d-pair-interleaved in LDS: element (d,i) at (d>>1)*16 + i*2 + (d&1),
// so u/logit/s math runs on adjacent float pairs -> v_pk_fma_f32 (fp32 peak needs pk).
// Softmax: no max subtraction (|logit| <~ 3, exp safe) -> only 4 serial swizzles for Z.
template <bool FIRST>
__global__ __launch_bounds__(BLOCK, 4)
void route_pass(const float* __restrict__ x, const float* __restrict__ W,
                const float* __restrict__ vsum, float* __restrict__ p_s)
{
    __shared__ float xs[B_TILE * XS_STRIDE];   // 12544 B
    __shared__ float Ws[KC * WS_PER_C];        // 15840 B

    const int tid    = threadIdx.x;
    const int warp   = tid >> 6;
    const int lane   = tid & 63;
    const int b_lane = lane & 3;
    const int slot   = lane >> 2;
    const bool active = (slot < N_N);
    const int  n     = active ? slot : (N_N - 1);  // idle lanes shadow n=9 (broadcast)
    const int  chunk = blockIdx.x;
    const int  gb0   = blockIdx.y * B_TILE;
    const int  bl    = warp * 4 + b_lane;          // 16 b's across 4 waves
    const int  gb    = gb0 + bl;
    const int  cbase = chunk * C_PER;

    // ---- stage x tile once (coalesced float4) ----
    {
        const float4* x4 = reinterpret_cast<const float4*>(x);
        for (int f = tid; f < (B_TILE * C_PER * I_N) / 4; f += BLOCK) {
            const int e   = f * 4;
            const int b2  = e / (C_PER * I_N);
            const int off = e - b2 * (C_PER * I_N);
            float4 v = x4[(size_t)(gb0 + b2) * (C_N * I_N / 4) + (size_t)cbase * 2 + (off >> 2)];
            *reinterpret_cast<float4*>(&xs[b2 * XS_STRIDE + off]) = v;
        }
    }

    // ---- vsum fragment (d-pair float2 layout matches u) ----
    float2 vs[8];
    if (!FIRST) {
        const float4* vp = reinterpret_cast<const float4*>(vsum + ((size_t)gb * N_N + n) * D_N);
        #pragma unroll
        for (int q = 0; q < 4; ++q) {
            float4 v = vp[q];
            vs[q * 2]     = make_float2(v.x, v.y);
            vs[q * 2 + 1] = make_float2(v.z, v.w);
        }
    }

    float2 s[8];
    #pragma unroll
    for (int d2 = 0; d2 < 8; ++d2) s[d2] = make_float2(0.f, 0.f);

    const float4* W4 = reinterpret_cast<const float4*>(W);

    for (int round = 0; round < ROUNDS; ++round) {
        __syncthreads();
        // ---- stage W for KC c's, d-pair interleaved: (d,i) -> (d>>1)*16 + i*2 + (d&1)
        const int c0 = cbase + round * KC;
        for (int f = tid; f < (KC * N_N * 128) / 4; f += BLOCK) {
            const int e  = f * 4;
            const int cc = e / (N_N * 128);
            const int r  = e - cc * (N_N * 128);
            const int nn = r >> 7;
            const int q  = r & 127;     // d*8 + i0
            const int d  = q >> 3;
            const int i0 = q & 7;       // 0 or 4
            float4 v = W4[(size_t)nn * (C_N * 128 / 4) + (size_t)(c0 + cc) * 32 + (q >> 2)];
            float* dst = &Ws[cc * WS_PER_C + nn * WS_STRIDE + (d >> 1) * 16 + (d & 1)];
            dst[(i0 + 0) * 2] = v.x;
            dst[(i0 + 1) * 2] = v.y;
            dst[(i0 + 2) * 2] = v.z;
            dst[(i0 + 3) * 2] = v.w;
        }
        __syncthreads();

        #pragma unroll
        for (int ccl = 0; ccl < KC; ++ccl) {
            const int crel = round * KC + ccl;
            const float* xp = &xs[bl * XS_STRIDE + crel * I_N];
            const float4 xa = *reinterpret_cast<const float4*>(xp);
            const float4 xb = *reinterpret_cast<const float4*>(xp + 4);
            const float* wp = &Ws[ccl * WS_PER_C + n * WS_STRIDE];

            float2 u[8];
            #pragma unroll
            for (int d2 = 0; d2 < 8; ++d2) {
                const float4 q0 = *reinterpret_cast<const float4*>(wp + d2 * 16);
                const float4 q1 = *reinterpret_cast<const float4*>(wp + d2 * 16 + 4);
                const float4 q2 = *reinterpret_cast<const float4*>(wp + d2 * 16 + 8);
                const float4 q3 = *reinterpret_cast<const float4*>(wp + d2 * 16 + 12);
                float ux = q0.x * xa.x, uy = q0.y * xa.x;
                ux = fmaf(q0.z, xa.y, ux); uy = fmaf(q0.w, xa.y, uy);
                ux = fmaf(q1.x, xa.z, ux); uy = fmaf(q1.y, xa.z, uy);
                ux = fmaf(q1.z, xa.w, ux); uy = fmaf(q1.w, xa.w, uy);
                ux = fmaf(q2.x, xb.x, ux); uy = fmaf(q2.y, xb.x, uy);
                ux = fmaf(q2.z, xb.y, ux); uy = fmaf(q2.w, xb.y, uy);
                ux = fmaf(q3.x, xb.z, ux); uy = fmaf(q3.y, xb.z, uy);
                ux = fmaf(q3.z, xb.w, ux); uy = fmaf(q3.w, xb.w, uy);
                u[d2] = make_float2(ux, uy);
            }

            float coef;
            if (FIRST) {
                coef = 1.0f / (float)N_N;
            } else {
                float lx = 0.f, ly = 0.f;
                #pragma unroll
                for (int d2 = 0; d2 < 8; ++d2) {
                    lx = fmaf(u[d2].x, vs[d2].x, lx);
                    ly = fmaf(u[d2].y, vs[d2].y, ly);
                }
                const float l = lx + ly;
                // |l| <= ~3 -> exp safe without max subtraction (saves 4 serial swizzles)
                const float e1 = active ? __expf(l) : 0.f;
                float Z = e1;
                #pragma unroll
                for (int off = 4; off < 64; off <<= 1) Z += __shfl_xor(Z, off);
                coef = e1 * __builtin_amdgcn_rcpf(Z);
            }
            #pragma unroll
            for (int d2 = 0; d2 < 8; ++d2) {
                s[d2].x = fmaf(coef, u[d2].x, s[d2].x);
                s[d2].y = fmaf(coef, u[d2].y, s[d2].y);
            }
        }
    }

    if (active) {
        float* outp = &p_s[(((size_t)chunk * B_N + gb) * N_N + n) * D_N];
        #pragma unroll
        for (int q = 0; q < 4; ++q) {
            *reinterpret_cast<float4*>(outp + q * 4) =
                make_float4(s[q * 2].x, s[q * 2].y, s[q * 2 + 1].x, s[q * 2 + 1].y);
        }
    }
}

// Sum partials over chunks, squash, then: phase0 vsum=v; phase1 vsum+=v; phase2 out=v.
__global__ __launch_bounds__(BLOCK)
void reduce_squash(const float* __restrict__ p_s, float* __restrict__ vsum,
                   float* __restrict__ out, int phase)
{
    const int tid = threadIdx.x;
    const int lg  = tid >> 4;
    const int d   = tid & 15;
    const int gg  = blockIdx.x * 16 + lg;   // 0..2559 == b*10+n

    float s = 0.f;
    for (int cc = 0; cc < C_CHUNKS; ++cc)
        s += p_s[((size_t)cc * (B_N * N_N) + gg) * D_N + d];

    float sq = s * s;
    #pragma unroll
    for (int off = 1; off < 16; off <<= 1) sq += __shfl_xor(sq, off, 64);

    const float scale = (sq / (1.f + sq)) / (sqrtf(sq) + 1e-8f);
    const float v = scale * s;

    if (phase == 0)      vsum[(size_t)gg * D_N + d] = v;
    else if (phase == 1) vsum[(size_t)gg * D_N + d] += v;
    else                 out[(size_t)gg * D_N + d] = v;
}

extern "C" void kernel_launch(void* const* d_in, const int* in_sizes, int n_in,
                              void* d_out, int out_size, void* d_ws, size_t ws_size,
                              hipStream_t stream)
{
    const float* x = (const float*)d_in[0];
    const float* W = (const float*)d_in[1];
    float* out  = (float*)d_out;
    float* vsum = (float*)d_ws;                         // B*N*D floats
    float* p_s  = vsum + (size_t)B_N * N_N * D_N;       // C_CHUNKS*B*N*D floats

    dim3 grid(C_CHUNKS, B_N / B_TILE);
    dim3 blk(BLOCK);
    dim3 rgrid((B_N * N_N) / 16);

    // pass 0: coef = 1/N (softmax of zero logits) -> v0
    route_pass<true><<<grid, blk, 0, stream>>>(x, W, nullptr, p_s);
    reduce_squash<<<rgrid, blk, 0, stream>>>(p_s, vsum, out, 0);
    // pass 1: logits = dot(u_hat, v0) -> v1, vsum = v0+v1
    route_pass<false><<<grid, blk, 0, stream>>>(x, W, vsum, p_s);
    reduce_squash<<<rgrid, blk, 0, stream>>>(p_s, vsum, out, 1);
    // pass 2: logits = dot(u_hat, v0+v1) -> output v2
    route_pass<false><<<grid, blk, 0, stream>>>(x, W, vsum, p_s);
    reduce_squash<<<rgrid, blk, 0, stream>>>(p_s, vsum, out, 2);
}